// Round 1
// baseline (118.423 us; speedup 1.0000x reference)
//
#include <hip/hip_runtime.h>

#define NBINS 10001

// ---------------------------------------------------------------------------
// Kernel 1: per-block LDS histogram (packed u32: tp<<16 | fp), flushed with
// packed u64 global atomics (tp<<32 | fp). Each block processes exactly
// N/1024 = 32768 elements -> 16-bit packed counts cannot overflow.
// ---------------------------------------------------------------------------
__global__ __launch_bounds__(256) void ks_hist(const float* __restrict__ preds,
                                               const float* __restrict__ tgts,
                                               unsigned long long* __restrict__ ghist,
                                               int n) {
    __shared__ unsigned int lh[NBINS];
    for (int i = threadIdx.x; i < NBINS; i += 256) lh[i] = 0u;
    __syncthreads();

    const int n4 = n >> 2;
    const float4* p4 = (const float4*)preds;
    const float4* t4 = (const float4*)tgts;
    const int tid = blockIdx.x * 256 + threadIdx.x;
    const int stride = gridDim.x * 256;

    for (int i = tid; i < n4; i += stride) {
        float4 p = p4[i];
        float4 t = t4[i];
        float px[4] = {p.x, p.y, p.z, p.w};
        float tx[4] = {t.x, t.y, t.z, t.w};
#pragma unroll
        for (int k = 0; k < 4; ++k) {
            // sigmoid; __expf overflow at extreme |x| is benign:
            //   x << 0: exp(-x)=inf -> s=0 -> bin 0
            //   x >> 0: exp(-x)=0   -> s=1.0f -> bin 10000
            float s = 1.0f / (1.0f + __expf(-px[k]));
            int b = (int)(10000.0f * s);
            unsigned int add = (tx[k] >= 0.5f) ? 0x10000u : 1u;
            atomicAdd(&lh[b], add);
        }
    }

    // scalar tail (n % 4), handled once by block 0
    if (blockIdx.x == 0) {
        int base = n4 << 2;
        int r = n - base;
        if ((int)threadIdx.x < r) {
            int i = base + threadIdx.x;
            float x = preds[i];
            float s = 1.0f / (1.0f + __expf(-x));
            int b = (int)(10000.0f * s);
            unsigned int add = (tgts[i] >= 0.5f) ? 0x10000u : 1u;
            atomicAdd(&lh[b], add);
        }
    }
    __syncthreads();

    for (int i = threadIdx.x; i < NBINS; i += 256) {
        unsigned int v = lh[i];
        if (v) {
            unsigned long long a =
                ((unsigned long long)(v >> 16) << 32) | (unsigned long long)(v & 0xFFFFu);
            atomicAdd(&ghist[i], a);
        }
    }
}

// ---------------------------------------------------------------------------
// Kernel 2: exact integer cumsum over 10001 bins (1 block, 1024 threads,
// 10 bins/thread + Hillis-Steele block scan), KS diff in double, block max.
// ---------------------------------------------------------------------------
__global__ __launch_bounds__(1024) void ks_scan(const unsigned long long* __restrict__ ghist,
                                                float* __restrict__ out) {
    __shared__ long long stp[1024];
    __shared__ long long sfp[1024];
    __shared__ double smx[1024];

    const int t = threadIdx.x;
    const int CH = 10;  // 1024*10 >= 10001
    const int lo = t * CH;

    unsigned long long loc[CH];
    long long tps = 0, fps = 0;
#pragma unroll
    for (int k = 0; k < CH; ++k) {
        int i = lo + k;
        unsigned long long v = (i < NBINS) ? ghist[i] : 0ull;
        loc[k] = v;
        tps += (long long)(v >> 32);
        fps += (long long)(v & 0xFFFFFFFFull);
    }
    stp[t] = tps;
    sfp[t] = fps;
    __syncthreads();

    // Hillis-Steele inclusive scan over per-thread partial sums
    for (int off = 1; off < 1024; off <<= 1) {
        long long a = stp[t], b = sfp[t];
        long long c = 0, d = 0;
        if (t >= off) { c = stp[t - off]; d = sfp[t - off]; }
        __syncthreads();
        stp[t] = a + c;
        sfp[t] = b + d;
        __syncthreads();
    }

    const long long TP = stp[1023];
    const long long FP = sfp[1023];
    const long long etp = stp[t] - tps;  // exclusive prefix for this thread
    const long long efp = sfp[t] - fps;

    const double invTP = 1.0 / (double)(TP > 0 ? TP : 1);
    const double invFP = 1.0 / (double)(FP > 0 ? FP : 1);

    double m = 0.0;
    long long tc = etp, fc = efp;
#pragma unroll
    for (int k = 0; k < CH; ++k) {
        unsigned long long v = loc[k];
        tc += (long long)(v >> 32);
        fc += (long long)(v & 0xFFFFFFFFull);
        double d = fabs((double)tc * invTP - (double)fc * invFP);
        m = (d > m) ? d : m;
    }

    smx[t] = m;
    __syncthreads();
    for (int off = 512; off > 0; off >>= 1) {
        if (t < off) smx[t] = smx[t] > smx[t + off] ? smx[t] : smx[t + off];
        __syncthreads();
    }
    if (t == 0) out[0] = (float)smx[0];
}

extern "C" void kernel_launch(void* const* d_in, const int* in_sizes, int n_in,
                              void* d_out, int out_size, void* d_ws, size_t ws_size,
                              hipStream_t stream) {
    const float* preds = (const float*)d_in[0];
    const float* tgts  = (const float*)d_in[1];
    const int n = in_sizes[0];

    unsigned long long* ghist = (unsigned long long*)d_ws;
    hipMemsetAsync(d_ws, 0, NBINS * sizeof(unsigned long long), stream);

    ks_hist<<<1024, 256, 0, stream>>>(preds, tgts, ghist, n);
    ks_scan<<<1, 1024, 0, stream>>>(ghist, (float*)d_out);
}

// Round 2
// 76.859 us; speedup vs baseline: 1.5408x; 1.5408x over previous
//
#include <hip/hip_runtime.h>

#define NBINS 10001
#define ROWP  10016          // padded row stride in u32 (64B-aligned rows)
#define HIST_BLOCKS 1024
#define HIST_THREADS 512
#define PCHUNK 128           // partial rows per reduce block

typedef unsigned int u32;
typedef unsigned long long u64;

__device__ __forceinline__ int ks_bin(float x) {
    // sigmoid via v_exp + v_rcp (approx rcp: ~1ulp, bin perturbation ~1e-7)
    float e = __expf(-x);
    float s = __builtin_amdgcn_rcpf(1.0f + e);
    int b = (int)(10000.0f * s);
    b = b < 0 ? 0 : b;
    return b > 10000 ? 10000 : b;
}

__device__ __forceinline__ void ks_acc4(u32* lh, float4 p, float4 t) {
    float px[4] = {p.x, p.y, p.z, p.w};
    float tx[4] = {t.x, t.y, t.z, t.w};
#pragma unroll
    for (int k = 0; k < 4; ++k) {
        int b = ks_bin(px[k]);
        u32 add = (tx[k] >= 0.5f) ? 0x10000u : 1u;
        atomicAdd(&lh[b], add);
    }
}

// ---------------------------------------------------------------------------
// Kernel 1: per-block LDS histogram (packed u32: tp<<16 | fp).
// Per block exactly 32768 elements -> 16-bit packed counts cannot overflow.
// Flush: plain coalesced stores of the partial histogram (use_partials), or
// fallback packed-u64 global atomics if ws is too small.
// ---------------------------------------------------------------------------
__global__ __launch_bounds__(HIST_THREADS) void ks_hist(
        const float* __restrict__ preds, const float* __restrict__ tgts,
        u64* __restrict__ ghist, u32* __restrict__ partials,
        int use_partials, int n) {
    __shared__ u32 lh[NBINS];
    for (int i = threadIdx.x; i < NBINS; i += HIST_THREADS) lh[i] = 0u;
    __syncthreads();

    const int n4 = n >> 2;
    const float4* p4 = (const float4*)preds;
    const float4* t4 = (const float4*)tgts;
    const int tid = blockIdx.x * HIST_THREADS + threadIdx.x;
    const int stride = gridDim.x * HIST_THREADS;

    int i = tid;
    for (; i + stride < n4; i += 2 * stride) {
        // 4 outstanding 16B loads before any compute
        float4 pa = p4[i];
        float4 pb = p4[i + stride];
        float4 ta = t4[i];
        float4 tb = t4[i + stride];
        ks_acc4(lh, pa, ta);
        ks_acc4(lh, pb, tb);
    }
    for (; i < n4; i += stride) {
        float4 p = p4[i];
        float4 t = t4[i];
        ks_acc4(lh, p, t);
    }

    // scalar tail (n % 4), handled once by block 0
    if (blockIdx.x == 0) {
        int base = n4 << 2;
        int r = n - base;
        if ((int)threadIdx.x < r) {
            int j = base + threadIdx.x;
            int b = ks_bin(preds[j]);
            u32 add = (tgts[j] >= 0.5f) ? 0x10000u : 1u;
            atomicAdd(&lh[b], add);
        }
    }
    __syncthreads();

    if (use_partials) {
        u32* mypart = partials + (size_t)blockIdx.x * ROWP;
        for (int b = threadIdx.x; b < NBINS; b += HIST_THREADS)
            mypart[b] = lh[b];
    } else {
        for (int b = threadIdx.x; b < NBINS; b += HIST_THREADS) {
            u32 v = lh[b];
            if (v) {
                u64 a = ((u64)(v >> 16) << 32) | (u64)(v & 0xFFFFu);
                atomicAdd(&ghist[b], a);
            }
        }
    }
}

// ---------------------------------------------------------------------------
// Kernel 2: reduce partial histograms. grid = (ceil(NBINS/256), P/PCHUNK).
// Each block sums PCHUNK rows for 256 consecutive bins (coalesced 1KB/iter),
// then one packed-u64 atomic per bin per row-chunk (~80K atomics total).
// ---------------------------------------------------------------------------
__global__ __launch_bounds__(256) void ks_reduce(const u32* __restrict__ partials,
                                                 u64* __restrict__ ghist) {
    int bin = blockIdx.x * 256 + threadIdx.x;
    if (bin >= NBINS) return;
    const u32* base = partials + (size_t)blockIdx.y * PCHUNK * ROWP + bin;
    u32 tp = 0, fp = 0;
#pragma unroll 4
    for (int k = 0; k < PCHUNK; ++k) {
        u32 v = base[(size_t)k * ROWP];
        tp += v >> 16;
        fp += v & 0xFFFFu;
    }
    atomicAdd(&ghist[bin], ((u64)tp << 32) | (u64)fp);
}

// ---------------------------------------------------------------------------
// Kernel 3: exact integer cumsum over 10001 bins (1 block, 1024 threads,
// 10 bins/thread + Hillis-Steele block scan), KS diff in double, block max.
// ---------------------------------------------------------------------------
__global__ __launch_bounds__(1024) void ks_scan(const u64* __restrict__ ghist,
                                                float* __restrict__ out) {
    __shared__ long long stp[1024];
    __shared__ long long sfp[1024];
    __shared__ double smx[1024];

    const int t = threadIdx.x;
    const int CH = 10;  // 1024*10 >= 10001
    const int lo = t * CH;

    u64 loc[CH];
    long long tps = 0, fps = 0;
#pragma unroll
    for (int k = 0; k < CH; ++k) {
        int i = lo + k;
        u64 v = (i < NBINS) ? ghist[i] : 0ull;
        loc[k] = v;
        tps += (long long)(v >> 32);
        fps += (long long)(v & 0xFFFFFFFFull);
    }
    stp[t] = tps;
    sfp[t] = fps;
    __syncthreads();

    for (int off = 1; off < 1024; off <<= 1) {
        long long a = stp[t], b = sfp[t];
        long long c = 0, d = 0;
        if (t >= off) { c = stp[t - off]; d = sfp[t - off]; }
        __syncthreads();
        stp[t] = a + c;
        sfp[t] = b + d;
        __syncthreads();
    }

    const long long TP = stp[1023];
    const long long FP = sfp[1023];
    const long long etp = stp[t] - tps;  // exclusive prefix
    const long long efp = sfp[t] - fps;

    const double invTP = 1.0 / (double)(TP > 0 ? TP : 1);
    const double invFP = 1.0 / (double)(FP > 0 ? FP : 1);

    double m = 0.0;
    long long tc = etp, fc = efp;
#pragma unroll
    for (int k = 0; k < CH; ++k) {
        u64 v = loc[k];
        tc += (long long)(v >> 32);
        fc += (long long)(v & 0xFFFFFFFFull);
        double d = fabs((double)tc * invTP - (double)fc * invFP);
        m = (d > m) ? d : m;
    }

    smx[t] = m;
    __syncthreads();
    for (int off = 512; off > 0; off >>= 1) {
        if (t < off) smx[t] = smx[t] > smx[t + off] ? smx[t] : smx[t + off];
        __syncthreads();
    }
    if (t == 0) out[0] = (float)smx[0];
}

extern "C" void kernel_launch(void* const* d_in, const int* in_sizes, int n_in,
                              void* d_out, int out_size, void* d_ws, size_t ws_size,
                              hipStream_t stream) {
    const float* preds = (const float*)d_in[0];
    const float* tgts  = (const float*)d_in[1];
    const int n = in_sizes[0];

    // ws layout: [ghist: 10001 u64][pad to 128KB][partials: 1024 x ROWP u32]
    const size_t part_off = 131072;
    const size_t need = part_off + (size_t)HIST_BLOCKS * ROWP * sizeof(u32);
    u64* ghist = (u64*)d_ws;
    u32* partials = (u32*)((char*)d_ws + part_off);
    const int use_partials = (ws_size >= need) ? 1 : 0;

    hipMemsetAsync(d_ws, 0, NBINS * sizeof(u64), stream);

    ks_hist<<<HIST_BLOCKS, HIST_THREADS, 0, stream>>>(preds, tgts, ghist,
                                                      partials, use_partials, n);
    if (use_partials) {
        dim3 rg((NBINS + 255) / 256, HIST_BLOCKS / PCHUNK);
        ks_reduce<<<rg, 256, 0, stream>>>(partials, ghist);
    }
    ks_scan<<<1, 1024, 0, stream>>>(ghist, (float*)d_out);
}

// Round 3
// 75.148 us; speedup vs baseline: 1.5759x; 1.0228x over previous
//
#include <hip/hip_runtime.h>

#define NBINS 10001
#define ROWP  10016          // padded row stride in u32 (64B-aligned rows)
#define HIST_BLOCKS 768      // exactly 3 blocks/CU on 256 CUs -> one generation
#define HIST_THREADS 512
#define PCHUNK 128           // partial rows per reduce block

typedef unsigned int u32;
typedef unsigned long long u64;

__device__ __forceinline__ int ks_bin(float x) {
    // sigmoid via v_exp + v_rcp (approx rcp ~1ulp; bin perturbation ~1e-7)
    float e = __expf(-x);
    float s = __builtin_amdgcn_rcpf(1.0f + e);
    int b = (int)(10000.0f * s);
    b = b < 0 ? 0 : b;
    return b > 10000 ? 10000 : b;
}

__device__ __forceinline__ void ks_acc4(u32* lh, float4 p, float4 t) {
    float px[4] = {p.x, p.y, p.z, p.w};
    float tx[4] = {t.x, t.y, t.z, t.w};
#pragma unroll
    for (int k = 0; k < 4; ++k) {
        int b = ks_bin(px[k]);
        u32 add = (tx[k] >= 0.5f) ? 0x10000u : 1u;
        atomicAdd(&lh[b], add);
    }
}

// ---------------------------------------------------------------------------
// Kernel 1: per-block LDS histogram (packed u32: tp<<16 | fp).
// Per block at most 45056 elements -> 16-bit packed counts cannot overflow.
// Depth-2 software pipeline: 2 iterations (4x16B loads) in flight over each
// 8-element compute body. Flush: coalesced partial-histogram stores.
// ---------------------------------------------------------------------------
__global__ __launch_bounds__(HIST_THREADS) void ks_hist(
        const float* __restrict__ preds, const float* __restrict__ tgts,
        u64* __restrict__ ghist, u32* __restrict__ partials,
        int use_partials, int n) {
    __shared__ u32 lh[NBINS];
    for (int i = threadIdx.x; i < NBINS; i += HIST_THREADS) lh[i] = 0u;
    __syncthreads();

    const int n4 = n >> 2;
    const float4* p4 = (const float4*)preds;
    const float4* t4 = (const float4*)tgts;
    const int tid = blockIdx.x * HIST_THREADS + threadIdx.x;
    const int stride = gridDim.x * HIST_THREADS;

    const int q = n4 / stride;
    const int r = n4 - q * stride;
    const int cnt = q + (tid < r ? 1 : 0);

    float4 pA, tA, pB, tB;
    if (cnt > 0) { pA = p4[tid]; tA = t4[tid]; }
    if (cnt > 1) { pB = p4[tid + stride]; tB = t4[tid + stride]; }
    int idx = tid + stride;
    for (int k = 2; k < cnt; ++k) {
        idx += stride;
        float4 pC = p4[idx];
        float4 tC = t4[idx];
        ks_acc4(lh, pA, tA);
        pA = pB; tA = tB;
        pB = pC; tB = tC;
    }
    if (cnt > 1) {
        ks_acc4(lh, pA, tA);
        ks_acc4(lh, pB, tB);
    } else if (cnt == 1) {
        ks_acc4(lh, pA, tA);
    }

    // scalar tail (n % 4), handled once by block 0
    if (blockIdx.x == 0) {
        int base = n4 << 2;
        int rem = n - base;
        if ((int)threadIdx.x < rem) {
            int j = base + threadIdx.x;
            int b = ks_bin(preds[j]);
            u32 add = (tgts[j] >= 0.5f) ? 0x10000u : 1u;
            atomicAdd(&lh[b], add);
        }
    }
    __syncthreads();

    if (use_partials) {
        u32* mypart = partials + (size_t)blockIdx.x * ROWP;
        for (int b = threadIdx.x; b < NBINS; b += HIST_THREADS)
            mypart[b] = lh[b];
    } else {
        for (int b = threadIdx.x; b < NBINS; b += HIST_THREADS) {
            u32 v = lh[b];
            if (v) {
                u64 a = ((u64)(v >> 16) << 32) | (u64)(v & 0xFFFFu);
                atomicAdd(&ghist[b], a);
            }
        }
    }
}

// ---------------------------------------------------------------------------
// Kernel 2: reduce partial histograms. grid = (ceil(NBINS/256), HIST_BLOCKS/PCHUNK).
// Each block sums PCHUNK rows for 256 consecutive bins (coalesced 1KB/iter),
// then one packed-u64 atomic per bin per row-chunk.
// ---------------------------------------------------------------------------
__global__ __launch_bounds__(256) void ks_reduce(const u32* __restrict__ partials,
                                                 u64* __restrict__ ghist) {
    int bin = blockIdx.x * 256 + threadIdx.x;
    if (bin >= NBINS) return;
    const u32* base = partials + (size_t)blockIdx.y * PCHUNK * ROWP + bin;
    u32 tp = 0, fp = 0;
#pragma unroll 4
    for (int k = 0; k < PCHUNK; ++k) {
        u32 v = base[(size_t)k * ROWP];
        tp += v >> 16;
        fp += v & 0xFFFFu;
    }
    atomicAdd(&ghist[bin], ((u64)tp << 32) | (u64)fp);
}

// ---------------------------------------------------------------------------
// Kernel 3: exact integer cumsum over 10001 bins (1 block, 1024 threads,
// 10 bins/thread + Hillis-Steele block scan), KS diff in double, block max.
// ---------------------------------------------------------------------------
__global__ __launch_bounds__(1024) void ks_scan(const u64* __restrict__ ghist,
                                                float* __restrict__ out) {
    __shared__ long long stp[1024];
    __shared__ long long sfp[1024];
    __shared__ double smx[1024];

    const int t = threadIdx.x;
    const int CH = 10;  // 1024*10 >= 10001
    const int lo = t * CH;

    u64 loc[CH];
    long long tps = 0, fps = 0;
#pragma unroll
    for (int k = 0; k < CH; ++k) {
        int i = lo + k;
        u64 v = (i < NBINS) ? ghist[i] : 0ull;
        loc[k] = v;
        tps += (long long)(v >> 32);
        fps += (long long)(v & 0xFFFFFFFFull);
    }
    stp[t] = tps;
    sfp[t] = fps;
    __syncthreads();

    for (int off = 1; off < 1024; off <<= 1) {
        long long a = stp[t], b = sfp[t];
        long long c = 0, d = 0;
        if (t >= off) { c = stp[t - off]; d = sfp[t - off]; }
        __syncthreads();
        stp[t] = a + c;
        sfp[t] = b + d;
        __syncthreads();
    }

    const long long TP = stp[1023];
    const long long FP = sfp[1023];
    const long long etp = stp[t] - tps;  // exclusive prefix
    const long long efp = sfp[t] - fps;

    const double invTP = 1.0 / (double)(TP > 0 ? TP : 1);
    const double invFP = 1.0 / (double)(FP > 0 ? FP : 1);

    double m = 0.0;
    long long tc = etp, fc = efp;
#pragma unroll
    for (int k = 0; k < CH; ++k) {
        u64 v = loc[k];
        tc += (long long)(v >> 32);
        fc += (long long)(v & 0xFFFFFFFFull);
        double d = fabs((double)tc * invTP - (double)fc * invFP);
        m = (d > m) ? d : m;
    }

    smx[t] = m;
    __syncthreads();
    for (int off = 512; off > 0; off >>= 1) {
        if (t < off) smx[t] = smx[t] > smx[t + off] ? smx[t] : smx[t + off];
        __syncthreads();
    }
    if (t == 0) out[0] = (float)smx[0];
}

extern "C" void kernel_launch(void* const* d_in, const int* in_sizes, int n_in,
                              void* d_out, int out_size, void* d_ws, size_t ws_size,
                              hipStream_t stream) {
    const float* preds = (const float*)d_in[0];
    const float* tgts  = (const float*)d_in[1];
    const int n = in_sizes[0];

    // ws layout: [ghist: 10001 u64][pad to 128KB][partials: HIST_BLOCKS x ROWP u32]
    const size_t part_off = 131072;
    const size_t need = part_off + (size_t)HIST_BLOCKS * ROWP * sizeof(u32);
    u64* ghist = (u64*)d_ws;
    u32* partials = (u32*)((char*)d_ws + part_off);
    const int use_partials = (ws_size >= need) ? 1 : 0;

    hipMemsetAsync(d_ws, 0, NBINS * sizeof(u64), stream);

    ks_hist<<<HIST_BLOCKS, HIST_THREADS, 0, stream>>>(preds, tgts, ghist,
                                                      partials, use_partials, n);
    if (use_partials) {
        dim3 rg((NBINS + 255) / 256, HIST_BLOCKS / PCHUNK);
        ks_reduce<<<rg, 256, 0, stream>>>(partials, ghist);
    }
    ks_scan<<<1, 1024, 0, stream>>>(ghist, (float*)d_out);
}